// Round 5
// baseline (154.387 us; speedup 1.0000x reference)
//
#include <hip/hip_runtime.h>
#include <math.h>

#define NPTS 200
#define NCH  13
#define BLK  256
#define FPB  (NPTS * NCH)          // 2600 floats per batch

// 4-byte-aligned float4 for dword-aligned (not 16B-aligned) vector loads
typedef float f4u __attribute__((ext_vector_type(4), aligned(4)));

// 12-byte packed store (align 4) for coalesced per-point output
typedef struct { float x, y, z; } f3s;

#define ACCUMULATE(Q0,Q1,Q2,Q3,Q4,Q5,Q6,Q7,Q8,Q9,Q10,Q11,Q12)               \
    {                                                                        \
        float wt = aa * (Q0) + bb;                                           \
        wt = fmaxf(wt, 0.f) + 1e-8f;                                         \
        const float v1x = fmaf(shift, (Q7),  (Q1));                          \
        const float v1y = fmaf(shift, (Q8),  (Q2));                          \
        const float v1z = fmaf(shift, (Q9),  (Q3));                          \
        const float v2x = fmaf(shift, (Q10), (Q4));                          \
        const float v2y = fmaf(shift, (Q11), (Q5));                          \
        const float v2z = fmaf(shift, (Q12), (Q6));                          \
        const float wv2x = wt * v2x, wv2y = wt * v2y, wv2z = wt * v2z;       \
        acc[0] += wt;                                                        \
        acc[1] += wt * v1x; acc[2] += wt * v1y; acc[3] += wt * v1z;          \
        acc[4] += wv2x;     acc[5] += wv2y;     acc[6] += wv2z;              \
        acc[7]  += wv2x * v1x; acc[8]  += wv2x * v1y; acc[9]  += wv2x * v1z; \
        acc[10] += wv2y * v1x; acc[11] += wv2y * v1y; acc[12] += wv2y * v1z; \
        acc[13] += wv2z * v1x; acc[14] += wv2z * v1y; acc[15] += wv2z * v1z; \
    }

// ---------------------------------------------------------------------------
// Fused v4: ZERO LDS, ZERO barriers, zero cross-wave communication.
// One wave owns one batch end-to-end; every construct here has previously
// passed on this harness:
//   - direct f4u loads, xyz2 kept in registers (ran in v2)
//   - full 6-level __shfl_xor butterfly: all 64 lanes end with all 16
//     totals in registers (ran in v1)
//   - all-lane redundant HW-approx Jacobi (intrinsics validated in v2;
//     redundant-per-wave structure validated in v1). Wave-level issue cost
//     is identical whether 1 or 64 lanes execute, so redundancy is free of
//     extra issue; it buys: no barriers, no block convoy behind a
//     4-thread-solve, no R,t broadcast.
//   - apply from registers; coalesced 12B/lane stores
// v2's remaining ~30us was the per-block convoy (two __syncthreads around
// a 3-5k-cycle dependent solve chain run by 4/256 threads). This removes it.
// ---------------------------------------------------------------------------
__global__ __launch_bounds__(BLK, 4) void fused_kernel(
    const float* __restrict__ net_in,   // (B, 200, 13)
    const float* __restrict__ shift_p,
    const float* __restrict__ a_p,
    const float* __restrict__ b_p,
    float* __restrict__ out)            // (B, 200, 3)
{
    const int tid = threadIdx.x;
    const int w   = tid >> 6;             // wave id = local batch
    const int l   = tid & 63;
    const int b   = blockIdx.x * 4 + w;   // global batch

    const float shift = shift_p[0];
    const float aa    = a_p[0];
    const float bb    = b_p[0];

    const float* src = net_in + (size_t)b * FPB;

    // ---- per-lane accumulation straight from global (52B/lane, coalesced;
    //      compiler software-pipelines the loads) ----
    float acc[16];
    #pragma unroll
    for (int k = 0; k < 16; ++k) acc[k] = 0.f;

    float sx2[4], sy2[4], sz2[4];

    #pragma unroll
    for (int j = 0; j < 4; ++j) {
        if (j < 3 || l < 8) {             // j<3 always valid; j==3 only l<8
            const float* q = src + (l + 64 * j) * NCH;
            const f4u v0 = *(const f4u*)(q);      // w, x1,y1,z1
            const f4u v1 = *(const f4u*)(q + 4);  // x2,y2,z2, n1x
            const f4u v2 = *(const f4u*)(q + 8);  // n1y,n1z, n2x,n2y
            const float q12 = q[12];              // n2z
            ACCUMULATE(v0.x, v0.y, v0.z, v0.w,
                       v1.x, v1.y, v1.z, v1.w,
                       v2.x, v2.y, v2.z, v2.w, q12)
            sx2[j] = v1.x; sy2[j] = v1.y; sz2[j] = v1.z;
        } else {
            sx2[j] = 0.f; sy2[j] = 0.f; sz2[j] = 0.f;
        }
    }

    // ---- full 64-lane xor-butterfly: every lane ends with all 16 totals ----
    #pragma unroll
    for (int k = 0; k < 16; ++k) {
        acc[k] += __shfl_xor(acc[k], 32, 64);
        acc[k] += __shfl_xor(acc[k], 16, 64);
        acc[k] += __shfl_xor(acc[k],  8, 64);
        acc[k] += __shfl_xor(acc[k],  4, 64);
        acc[k] += __shfl_xor(acc[k],  2, 64);
        acc[k] += __shfl_xor(acc[k],  1, 64);
    }

    // ---- Horn quaternion / 4x4 Jacobi: redundant on all 64 lanes ----
    const float W = acc[0];
    const float invW = __builtin_amdgcn_rcpf(W);
    const float v1cx = acc[1] * invW, v1cy = acc[2] * invW, v1cz = acc[3] * invW;
    const float v2cx = acc[4] * invW, v2cy = acc[5] * invW, v2cz = acc[6] * invW;

    const float Sxx = acc[7]  - W * v2cx * v1cx;
    const float Sxy = acc[8]  - W * v2cx * v1cy;
    const float Sxz = acc[9]  - W * v2cx * v1cz;
    const float Syx = acc[10] - W * v2cy * v1cx;
    const float Syy = acc[11] - W * v2cy * v1cy;
    const float Syz = acc[12] - W * v2cy * v1cz;
    const float Szx = acc[13] - W * v2cz * v1cx;
    const float Szy = acc[14] - W * v2cz * v1cy;
    const float Szz = acc[15] - W * v2cz * v1cz;

    float Am[4][4];
    Am[0][0] = Sxx + Syy + Szz;
    Am[0][1] = Syz - Szy;  Am[0][2] = Szx - Sxz;  Am[0][3] = Sxy - Syx;
    Am[1][1] = Sxx - Syy - Szz;
    Am[1][2] = Sxy + Syx;  Am[1][3] = Szx + Sxz;
    Am[2][2] = -Sxx + Syy - Szz;
    Am[2][3] = Syz + Szy;
    Am[3][3] = -Sxx - Syy + Szz;
    Am[1][0] = Am[0][1]; Am[2][0] = Am[0][2]; Am[3][0] = Am[0][3];
    Am[2][1] = Am[1][2]; Am[3][1] = Am[1][3]; Am[3][2] = Am[2][3];

    float Vm[4][4] = {{1,0,0,0},{0,1,0,0},{0,0,1,0},{0,0,0,1}};

    const int prs[6][2] = {{0,1},{0,2},{0,3},{1,2},{1,3},{2,3}};
    for (int sweep = 0; sweep < 5; ++sweep) {
        #pragma unroll
        for (int r = 0; r < 6; ++r) {
            const int p = prs[r][0], q = prs[r][1];
            float apq = Am[p][q];
            if (apq != 0.0f) {                    // wave-uniform branch
                float tau = (Am[q][q] - Am[p][p]) * 0.5f *
                            __builtin_amdgcn_rcpf(apq);
                float t = copysignf(1.0f, tau) * __builtin_amdgcn_rcpf(
                            fabsf(tau) +
                            __builtin_amdgcn_sqrtf(fmaf(tau, tau, 1.0f)));
                float c = __builtin_amdgcn_rsqf(fmaf(t, t, 1.0f));
                float s = t * c;
                #pragma unroll
                for (int k = 0; k < 4; ++k) {
                    float a1 = Am[p][k], a2 = Am[q][k];
                    Am[p][k] = c * a1 - s * a2;
                    Am[q][k] = s * a1 + c * a2;
                }
                #pragma unroll
                for (int k = 0; k < 4; ++k) {
                    float a1 = Am[k][p], a2 = Am[k][q];
                    Am[k][p] = c * a1 - s * a2;
                    Am[k][q] = s * a1 + c * a2;
                }
                #pragma unroll
                for (int k = 0; k < 4; ++k) {
                    float a1 = Vm[k][p], a2 = Vm[k][q];
                    Vm[k][p] = c * a1 - s * a2;
                    Vm[k][q] = s * a1 + c * a2;
                }
            }
        }
    }

    // ---- best eigenvector: constant-indexed compare chain ----
    float bd = Am[0][0];
    float q0 = Vm[0][0], qx = Vm[1][0], qy = Vm[2][0], qz = Vm[3][0];
    if (Am[1][1] > bd) { bd = Am[1][1]; q0 = Vm[0][1]; qx = Vm[1][1]; qy = Vm[2][1]; qz = Vm[3][1]; }
    if (Am[2][2] > bd) { bd = Am[2][2]; q0 = Vm[0][2]; qx = Vm[1][2]; qy = Vm[2][2]; qz = Vm[3][2]; }
    if (Am[3][3] > bd) { bd = Am[3][3]; q0 = Vm[0][3]; qx = Vm[1][3]; qy = Vm[2][3]; qz = Vm[3][3]; }

    // renormalize (approx rotations leave ~1e-5 norm drift)
    const float qn = __builtin_amdgcn_rsqf(q0*q0 + qx*qx + qy*qy + qz*qz);
    q0 *= qn; qx *= qn; qy *= qn; qz *= qn;

    const float R00 = q0*q0 + qx*qx - qy*qy - qz*qz;
    const float R01 = 2.0f * (qx*qy - q0*qz);
    const float R02 = 2.0f * (qx*qz + q0*qy);
    const float R10 = 2.0f * (qx*qy + q0*qz);
    const float R11 = q0*q0 - qx*qx + qy*qy - qz*qz;
    const float R12 = 2.0f * (qy*qz - q0*qx);
    const float R20 = 2.0f * (qx*qz - q0*qy);
    const float R21 = 2.0f * (qy*qz + q0*qx);
    const float R22 = q0*q0 - qx*qx - qy*qy + qz*qz;

    const float tx = v1cx - (R00 * v2cx + R01 * v2cy + R02 * v2cz);
    const float ty = v1cy - (R10 * v2cx + R11 * v2cy + R12 * v2cz);
    const float tz = v1cz - (R20 * v2cx + R21 * v2cy + R22 * v2cz);

    // ---- apply from registers; coalesced 12B/lane stores ----
    float* ob = out + (size_t)b * (NPTS * 3);
    #pragma unroll
    for (int j = 0; j < 4; ++j) {
        if (j < 3 || l < 8) {
            const int p = l + 64 * j;
            const float X = sx2[j], Y = sy2[j], Z = sz2[j];
            f3s o3;
            o3.x = R00 * X + R01 * Y + R02 * Z + tx;
            o3.y = R10 * X + R11 * Y + R12 * Z + ty;
            o3.z = R20 * X + R21 * Y + R22 * Z + tz;
            *(f3s*)(ob + p * 3) = o3;
        }
    }
}

extern "C" void kernel_launch(void* const* d_in, const int* in_sizes, int n_in,
                              void* d_out, int out_size, void* d_ws, size_t ws_size,
                              hipStream_t stream) {
    const float* net_in  = (const float*)d_in[0];
    const float* shift_p = (const float*)d_in[1];
    const float* a_p     = (const float*)d_in[2];
    const float* b_p     = (const float*)d_in[3];
    float* out = (float*)d_out;

    const int B = in_sizes[0] / FPB;             // 8192
    (void)d_ws; (void)ws_size; (void)n_in; (void)out_size;

    fused_kernel<<<B / 4, BLK, 0, stream>>>(net_in, shift_p, a_p, b_p, out);
}